// Round 1
// baseline (4294.576 us; speedup 1.0000x reference)
//
#include <hip/hip_runtime.h>

#define NN 50000
#define NE 1600000
#define NR 8
#define ND 128
#define NL 3
#define LN_EPS 1e-5f

// h = emb[x]
__global__ __launch_bounds__(256) void k_gather(const int* __restrict__ x,
                                                const float* __restrict__ emb,
                                                float* __restrict__ h) {
    int i = blockIdx.x * 256 + threadIdx.x;
    if (i >= NN * ND) return;
    int n = i >> 7, d = i & 127;
    h[i] = emb[(size_t)x[n] * ND + d];
}

// cnt[r*N + dst] += 1 per edge
__global__ __launch_bounds__(256) void k_count(const int* __restrict__ dst,
                                               const int* __restrict__ et,
                                               int* __restrict__ cnt) {
    int e = blockIdx.x * 256 + threadIdx.x;
    if (e >= NE) return;
    atomicAdd(&cnt[et[e] * NN + dst[e]], 1);
}

__global__ __launch_bounds__(256) void k_inv(const int* __restrict__ cnt,
                                             float* __restrict__ inv) {
    int i = blockIdx.x * 256 + threadIdx.x;
    if (i >= NR * NN) return;
    int c = cnt[i];
    inv[i] = 1.0f / (float)(c > 1 ? c : 1);
}

// For edges of relation `rel`: S[dst,:] += h[src,:]   (one wave per edge-slot, 16 edges/wave)
__global__ __launch_bounds__(256) void k_scatter(const int* __restrict__ src,
                                                 const int* __restrict__ dst,
                                                 const int* __restrict__ et,
                                                 const float* __restrict__ h,
                                                 float* __restrict__ S, int rel) {
    int wave = threadIdx.x >> 6, lane = threadIdx.x & 63;
    int e0 = blockIdx.x * 64 + wave * 16;
    for (int i = 0; i < 16; i++) {
        int e = e0 + i;
        if (e >= NE) return;
        if (et[e] != rel) continue;              // wave-uniform branch
        int s = src[e], t = dst[e];
        atomicAdd(&S[(size_t)t * ND + lane],      h[(size_t)s * ND + lane]);
        atomicAdd(&S[(size_t)t * ND + 64 + lane], h[(size_t)s * ND + 64 + lane]);
    }
}

// agg[n,f] += scale(n) * sum_d S[n,d] * W[d,f]; scale = inv[n] or 1 (inv==null)
// block: 256 threads, tile 64 rows x 128 cols; micro-tile 8 rows x 4 cols/thread
__global__ __launch_bounds__(256) void k_matmul_acc(const float* __restrict__ S,
                                                    const float* __restrict__ inv,
                                                    const float* __restrict__ W,
                                                    float* __restrict__ agg) {
    __shared__ float SL[64][ND];
    int tid = threadIdx.x;
    int n0 = blockIdx.x * 64;

    const float4* S4 = (const float4*)(S + (size_t)n0 * ND);
    float4* SL4 = (float4*)&SL[0][0];
#pragma unroll
    for (int i = 0; i < 8; i++) {
        int idx = tid + i * 256;
        int row = idx >> 5;                      // 32 float4 per row
        float4 v = make_float4(0.f, 0.f, 0.f, 0.f);
        if (n0 + row < NN) v = S4[idx];
        SL4[idx] = v;
    }
    __syncthreads();

    int tx = tid & 31, ty = tid >> 5;
    int c0 = tx * 4, r0 = ty * 8;
    float acc[8][4];
#pragma unroll
    for (int j = 0; j < 8; j++)
#pragma unroll
        for (int k = 0; k < 4; k++) acc[j][k] = 0.f;

    for (int d = 0; d < ND; d++) {
        float4 w = *(const float4*)&W[d * ND + c0];
#pragma unroll
        for (int j = 0; j < 8; j++) {
            float s = SL[r0 + j][d];
            acc[j][0] += s * w.x;
            acc[j][1] += s * w.y;
            acc[j][2] += s * w.z;
            acc[j][3] += s * w.w;
        }
    }

#pragma unroll
    for (int j = 0; j < 8; j++) {
        int n = n0 + r0 + j;
        if (n >= NN) continue;
        float sc = inv ? inv[n] : 1.0f;
        float4* p = (float4*)&agg[(size_t)n * ND + c0];
        float4 o = *p;
        o.x += acc[j][0] * sc;
        o.y += acc[j][1] * sc;
        o.z += acc[j][2] * sc;
        o.w += acc[j][3] * sc;
        *p = o;
    }
}

// out = relu(layernorm(agg + bias) * gamma + beta) [+ h_old if add_res]; one wave per node
__global__ __launch_bounds__(256) void k_ln(const float* __restrict__ agg,
                                            const float* __restrict__ bias,
                                            const float* __restrict__ gamma,
                                            const float* __restrict__ beta,
                                            const float* __restrict__ h_old,
                                            float* __restrict__ h_out,
                                            int add_res) {
    int wave = threadIdx.x >> 6, lane = threadIdx.x & 63;
    int n = blockIdx.x * 4 + wave;
    if (n >= NN) return;
    size_t base = (size_t)n * ND;
    float v0 = agg[base + lane] + bias[lane];
    float v1 = agg[base + 64 + lane] + bias[64 + lane];
    float sum = v0 + v1;
#pragma unroll
    for (int off = 32; off > 0; off >>= 1) sum += __shfl_xor(sum, off, 64);
    float mu = sum * (1.0f / ND);
    float d0 = v0 - mu, d1 = v1 - mu;
    float vs = d0 * d0 + d1 * d1;
#pragma unroll
    for (int off = 32; off > 0; off >>= 1) vs += __shfl_xor(vs, off, 64);
    float r = rsqrtf(vs * (1.0f / ND) + LN_EPS);
    float o0 = fmaxf(d0 * r * gamma[lane] + beta[lane], 0.0f);
    float o1 = fmaxf(d1 * r * gamma[64 + lane] + beta[64 + lane], 0.0f);
    if (add_res) {
        o0 += h_old[base + lane];
        o1 += h_old[base + 64 + lane];
    }
    h_out[base + lane] = o0;
    h_out[base + 64 + lane] = o1;
}

extern "C" void kernel_launch(void* const* d_in, const int* in_sizes, int n_in,
                              void* d_out, int out_size, void* d_ws, size_t ws_size,
                              hipStream_t stream) {
    const int*   x      = (const int*)d_in[0];
    const int*   ei     = (const int*)d_in[1];   // [2, E] flat
    const int*   et     = (const int*)d_in[2];
    const float* emb    = (const float*)d_in[3];
    const float* w_rel  = (const float*)d_in[4]; // [L, R, D, D]
    const float* w_root = (const float*)d_in[5]; // [L, D, D]
    const float* bias   = (const float*)d_in[6]; // [L, D]
    const float* gamma  = (const float*)d_in[7];
    const float* beta   = (const float*)d_in[8];
    float* out = (float*)d_out;

    char* ws = (char*)d_ws;
    // layout: h (25.6MB) | agg (25.6MB) | S (25.6MB) | cnt (1.6MB) | inv (1.6MB) = 80MB
    float* h   = (float*)(ws);
    float* agg = (float*)(ws + 25600000);
    float* S   = (float*)(ws + 51200000);
    int*   cnt = (int*)  (ws + 76800000);
    float* inv = (float*)(ws + 78400000);

    const int* src = ei;
    const int* dst = ei + NE;

    k_gather<<<(NN * ND + 255) / 256, 256, 0, stream>>>(x, emb, h);
    hipMemsetAsync(cnt, 0, NR * NN * sizeof(int), stream);
    k_count<<<(NE + 255) / 256, 256, 0, stream>>>(dst, et, cnt);
    k_inv<<<(NR * NN + 255) / 256, 256, 0, stream>>>(cnt, inv);

    for (int l = 0; l < NL; l++) {
        hipMemsetAsync(agg, 0, (size_t)NN * ND * sizeof(float), stream);
        for (int r = 0; r < NR; r++) {
            hipMemsetAsync(S, 0, (size_t)NN * ND * sizeof(float), stream);
            k_scatter<<<(NE + 63) / 64, 256, 0, stream>>>(src, dst, et, h, S, r);
            k_matmul_acc<<<(NN + 63) / 64, 256, 0, stream>>>(
                S, inv + r * NN, w_rel + ((size_t)l * NR + r) * ND * ND, agg);
        }
        // root transform: agg += h @ w_root[l]
        k_matmul_acc<<<(NN + 63) / 64, 256, 0, stream>>>(
            h, nullptr, w_root + (size_t)l * ND * ND, agg);
        float* hout = (l == NL - 1) ? out : h;
        k_ln<<<(NN + 3) / 4, 256, 0, stream>>>(
            agg, bias + l * ND, gamma + l * ND, beta + l * ND, h, hout, l > 0);
    }
}

// Round 2
// 1563.074 us; speedup vs baseline: 2.7475x; 2.7475x over previous
//
#include <hip/hip_runtime.h>

#define NN 50000
#define NE 1600000
#define NR 8
#define ND 128
#define NL 3
#define RN (NR * NN)          // 400000 segments
#define SCAN_BLK 1024         // elements per scan block
#define NB ((RN + SCAN_BLK - 1) / SCAN_BLK)  // 391
#define LN_EPS 1e-5f

// h = emb[x]
__global__ __launch_bounds__(256) void k_gather(const int* __restrict__ x,
                                                const float* __restrict__ emb,
                                                float* __restrict__ h) {
    int i = blockIdx.x * 256 + threadIdx.x;
    if (i >= NN * ND) return;
    int n = i >> 7;
    h[i] = emb[(size_t)x[n] * ND + (i & 127)];
}

// cnt[r*N + dst] += 1 per edge
__global__ __launch_bounds__(256) void k_count(const int* __restrict__ dst,
                                               const int* __restrict__ et,
                                               int* __restrict__ cnt) {
    int e = blockIdx.x * 256 + threadIdx.x;
    if (e >= NE) return;
    atomicAdd(&cnt[et[e] * NN + dst[e]], 1);
}

__global__ __launch_bounds__(256) void k_inv(const int* __restrict__ cnt,
                                             float* __restrict__ inv) {
    int i = blockIdx.x * 256 + threadIdx.x;
    if (i >= RN) return;
    int c = cnt[i];
    inv[i] = 1.0f / (float)(c > 1 ? c : 1);
}

// ---- prefix sum over cnt[RN] -> rowstart (exclusive) ----
__global__ __launch_bounds__(256) void k_scan1(const int* __restrict__ cnt,
                                               int* __restrict__ rowstart,
                                               int* __restrict__ bsum) {
    __shared__ int tmp[256];
    int t = threadIdx.x;
    int base = blockIdx.x * SCAN_BLK + t * 4;
    int v[4];
#pragma unroll
    for (int i = 0; i < 4; i++) v[i] = (base + i < RN) ? cnt[base + i] : 0;
    int local = v[0] + v[1] + v[2] + v[3];
    tmp[t] = local;
    __syncthreads();
    for (int off = 1; off < 256; off <<= 1) {
        int x = (t >= off) ? tmp[t - off] : 0;
        __syncthreads();
        tmp[t] += x;
        __syncthreads();
    }
    int run = tmp[t] - local;               // exclusive within block
    if (t == 255) bsum[blockIdx.x] = tmp[t];
#pragma unroll
    for (int i = 0; i < 4; i++) {
        if (base + i < RN) rowstart[base + i] = run;
        run += v[i];
    }
}

__global__ __launch_bounds__(256) void k_scan2(const int* __restrict__ bsum,
                                               int* __restrict__ boff) {
    __shared__ int tmp[256];
    int t = threadIdx.x;
    int v0 = (2 * t < NB) ? bsum[2 * t] : 0;
    int v1 = (2 * t + 1 < NB) ? bsum[2 * t + 1] : 0;
    int local = v0 + v1;
    tmp[t] = local;
    __syncthreads();
    for (int off = 1; off < 256; off <<= 1) {
        int x = (t >= off) ? tmp[t - off] : 0;
        __syncthreads();
        tmp[t] += x;
        __syncthreads();
    }
    int excl = tmp[t] - local;
    if (2 * t < NB) boff[2 * t] = excl;
    if (2 * t + 1 < NB) boff[2 * t + 1] = excl + v0;
}

__global__ __launch_bounds__(256) void k_scan3(int* __restrict__ rowstart,
                                               const int* __restrict__ boff) {
    int i = blockIdx.x * 256 + threadIdx.x;
    if (i < RN) rowstart[i] += boff[i >> 10];
    if (i == 0) rowstart[RN] = NE;
}

// fill adj: consumes cnt as a cursor (inv already computed)
__global__ __launch_bounds__(256) void k_fill(const int* __restrict__ src,
                                              const int* __restrict__ dst,
                                              const int* __restrict__ et,
                                              const int* __restrict__ rowstart,
                                              int* __restrict__ cnt,
                                              int* __restrict__ adj) {
    int e = blockIdx.x * 256 + threadIdx.x;
    if (e >= NE) return;
    int seg = et[e] * NN + dst[e];
    int c = atomicSub(&cnt[seg], 1);
    adj[rowstart[seg] + c - 1] = src[e];
}

// Fused RGCN layer: per block = 64 nodes × 128 cols.
// For each relation: build mean-aggregated tile in LDS from CSR, matmul-acc.
// Then root transform, then bias+LN+ReLU+residual epilogue.
__global__ __launch_bounds__(256) void k_layer(const float* __restrict__ h_in,
                                               const int* __restrict__ adj,
                                               const int* __restrict__ rowstart,
                                               const float* __restrict__ inv,
                                               const float* __restrict__ w_rel,
                                               const float* __restrict__ w_root,
                                               const float* __restrict__ bias,
                                               const float* __restrict__ gamma,
                                               const float* __restrict__ beta,
                                               float* __restrict__ h_out,
                                               int add_res) {
    __shared__ float SL[64][ND];
    int tid = threadIdx.x;
    int n0 = blockIdx.x * 64;
    int wave = tid >> 6, lane = tid & 63;
    int tx = tid & 31, ty = tid >> 5;
    int c0 = tx * 4, r0 = ty * 8;

    float acc[8][4];
#pragma unroll
    for (int j = 0; j < 8; j++)
#pragma unroll
        for (int k = 0; k < 4; k++) acc[j][k] = 0.f;

    for (int r = 0; r < NR; r++) {
        // gather phase: wave handles 16 rows
        for (int i = 0; i < 16; i++) {
            int row = wave * 16 + i;
            int g = n0 + row;
            float a0 = 0.f, a1 = 0.f;
            if (g < NN) {
                int seg = r * NN + g;
                int st = rowstart[seg], en = rowstart[seg + 1];
                float b0 = 0.f, b1 = 0.f;
                int p = st;
                for (; p + 1 < en; p += 2) {        // 2-way ILP
                    int s0 = adj[p], s1 = adj[p + 1];
                    a0 += h_in[(size_t)s0 * ND + lane];
                    a1 += h_in[(size_t)s0 * ND + 64 + lane];
                    b0 += h_in[(size_t)s1 * ND + lane];
                    b1 += h_in[(size_t)s1 * ND + 64 + lane];
                }
                if (p < en) {
                    int s0 = adj[p];
                    a0 += h_in[(size_t)s0 * ND + lane];
                    a1 += h_in[(size_t)s0 * ND + 64 + lane];
                }
                float sc = inv[seg];
                a0 = (a0 + b0) * sc;
                a1 = (a1 + b1) * sc;
            }
            SL[row][lane] = a0;
            SL[row][64 + lane] = a1;
        }
        __syncthreads();
        const float* W = w_rel + (size_t)r * ND * ND;
        for (int d = 0; d < ND; d++) {
            float4 w = *(const float4*)&W[d * ND + c0];
#pragma unroll
            for (int j = 0; j < 8; j++) {
                float s = SL[r0 + j][d];
                acc[j][0] += s * w.x;
                acc[j][1] += s * w.y;
                acc[j][2] += s * w.z;
                acc[j][3] += s * w.w;
            }
        }
        __syncthreads();
    }

    // root transform: M = h_in tile
    {
        const float4* H4 = (const float4*)(h_in + (size_t)n0 * ND);
        float4* SL4 = (float4*)&SL[0][0];
#pragma unroll
        for (int i = 0; i < 8; i++) {
            int idx = tid + i * 256;
            int row = idx >> 5;
            float4 v = make_float4(0.f, 0.f, 0.f, 0.f);
            if (n0 + row < NN) v = H4[idx];
            SL4[idx] = v;
        }
        __syncthreads();
        for (int d = 0; d < ND; d++) {
            float4 w = *(const float4*)&w_root[d * ND + c0];
#pragma unroll
            for (int j = 0; j < 8; j++) {
                float s = SL[r0 + j][d];
                acc[j][0] += s * w.x;
                acc[j][1] += s * w.y;
                acc[j][2] += s * w.z;
                acc[j][3] += s * w.w;
            }
        }
        __syncthreads();
    }

    // epilogue: stash acc in SL, then LN per row
#pragma unroll
    for (int j = 0; j < 8; j++)
        *(float4*)&SL[r0 + j][c0] = make_float4(acc[j][0], acc[j][1], acc[j][2], acc[j][3]);
    __syncthreads();

    for (int i = 0; i < 16; i++) {
        int row = wave * 16 + i;
        int g = n0 + row;
        if (g >= NN) continue;                       // wave-uniform
        float v0 = SL[row][lane] + bias[lane];
        float v1 = SL[row][64 + lane] + bias[64 + lane];
        float sum = v0 + v1;
#pragma unroll
        for (int off = 32; off > 0; off >>= 1) sum += __shfl_xor(sum, off, 64);
        float mu = sum * (1.0f / ND);
        float d0 = v0 - mu, d1 = v1 - mu;
        float vs = d0 * d0 + d1 * d1;
#pragma unroll
        for (int off = 32; off > 0; off >>= 1) vs += __shfl_xor(vs, off, 64);
        float rr = rsqrtf(vs * (1.0f / ND) + LN_EPS);
        float o0 = fmaxf(d0 * rr * gamma[lane] + beta[lane], 0.0f);
        float o1 = fmaxf(d1 * rr * gamma[64 + lane] + beta[64 + lane], 0.0f);
        size_t base = (size_t)g * ND;
        if (add_res) {
            o0 += h_in[base + lane];
            o1 += h_in[base + 64 + lane];
        }
        h_out[base + lane] = o0;
        h_out[base + 64 + lane] = o1;
    }
}

extern "C" void kernel_launch(void* const* d_in, const int* in_sizes, int n_in,
                              void* d_out, int out_size, void* d_ws, size_t ws_size,
                              hipStream_t stream) {
    const int*   x      = (const int*)d_in[0];
    const int*   ei     = (const int*)d_in[1];
    const int*   et     = (const int*)d_in[2];
    const float* emb    = (const float*)d_in[3];
    const float* w_rel  = (const float*)d_in[4];
    const float* w_root = (const float*)d_in[5];
    const float* bias   = (const float*)d_in[6];
    const float* gamma  = (const float*)d_in[7];
    const float* beta   = (const float*)d_in[8];
    float* out = (float*)d_out;

    char* ws = (char*)d_ws;
    float* h_a      = (float*)(ws);                  // 25.6 MB
    float* h_b      = (float*)(ws + 25600000);       // 25.6 MB
    int*   cnt      = (int*)  (ws + 51200000);       // 1.6 MB
    float* inv      = (float*)(ws + 52800000);       // 1.6 MB
    int*   rowstart = (int*)  (ws + 54400000);       // 1.6 MB + 4
    int*   bsum     = (int*)  (ws + 56000064);
    int*   boff     = (int*)  (ws + 56001664);
    int*   adj      = (int*)  (ws + 56003264);       // 6.4 MB

    const int* src = ei;
    const int* dst = ei + NE;

    hipMemsetAsync(cnt, 0, RN * sizeof(int), stream);
    k_gather<<<(NN * ND + 255) / 256, 256, 0, stream>>>(x, emb, h_a);
    k_count<<<(NE + 255) / 256, 256, 0, stream>>>(dst, et, cnt);
    k_inv<<<(RN + 255) / 256, 256, 0, stream>>>(cnt, inv);
    k_scan1<<<NB, 256, 0, stream>>>(cnt, rowstart, bsum);
    k_scan2<<<1, 256, 0, stream>>>(bsum, boff);
    k_scan3<<<(RN + 255) / 256, 256, 0, stream>>>(rowstart, boff);
    k_fill<<<(NE + 255) / 256, 256, 0, stream>>>(src, dst, et, rowstart, cnt, adj);

    float* h_cur = h_a;
    float* h_nxt = h_b;
    for (int l = 0; l < NL; l++) {
        float* hout = (l == NL - 1) ? out : h_nxt;
        k_layer<<<(NN + 63) / 64, 256, 0, stream>>>(
            h_cur, adj, rowstart, inv,
            w_rel + (size_t)l * NR * ND * ND, w_root + (size_t)l * ND * ND,
            bias + l * ND, gamma + l * ND, beta + l * ND, hout, l > 0);
        float* t = h_cur; h_cur = h_nxt; h_nxt = t;
    }
}

// Round 3
// 1179.963 us; speedup vs baseline: 3.6396x; 1.3247x over previous
//
#include <hip/hip_runtime.h>

#define NN 50000
#define NE 1600000
#define NR 8
#define ND 128
#define NL 3
#define RN (NR * NN)
#define SCAN_BLK 1024
#define NB ((RN + SCAN_BLK - 1) / SCAN_BLK)  // 391
#define LN_EPS 1e-5f
#define PADB 136   // bf16 elems per LDS tile row (128 + 8 pad -> conflict-free b128 reads)
#define PADF 132   // f32 elems per epilogue scratch row

typedef __attribute__((ext_vector_type(8))) short short8;
typedef __attribute__((ext_vector_type(4))) float float4v;

__device__ __forceinline__ float bflo(unsigned u) { return __uint_as_float(u << 16); }
__device__ __forceinline__ float bfhi(unsigned u) { return __uint_as_float(u & 0xFFFF0000u); }
__device__ __forceinline__ unsigned f2bf(float f) {
    unsigned u = __float_as_uint(f);
    return (u + 0x7FFFu + ((u >> 16) & 1u)) >> 16;   // RNE
}
__device__ __forceinline__ unsigned pack2(float lo, float hi) {
    return f2bf(lo) | (f2bf(hi) << 16);
}

// h(bf16x2 packed) = emb[x]
__global__ __launch_bounds__(256) void k_gather(const int* __restrict__ x,
                                                const float* __restrict__ emb,
                                                unsigned* __restrict__ h) {
    int i = blockIdx.x * 256 + threadIdx.x;       // over NN*64 dwords
    if (i >= NN * 64) return;
    int n = i >> 6, dw = i & 63;
    float2 v = *(const float2*)&emb[(size_t)x[n] * ND + 2 * dw];
    h[i] = pack2(v.x, v.y);
}

// weights -> bf16 B-fragment layout: wb[m][((kk*8+ft)*64+lane)*8+j] = W_m[kk*32+(lane>>4)*8+j][ft*16+(lane&15)]
// matrices 0..23 = w_rel[l*8+r], 24..26 = w_root[l]
__global__ __launch_bounds__(256) void k_wprep(const float* __restrict__ w_rel,
                                               const float* __restrict__ w_root,
                                               unsigned short* __restrict__ wb) {
    int i = blockIdx.x * 256 + threadIdx.x;
    if (i >= 27 * 16384) return;
    int m = i >> 14;
    int idx = i & 16383;
    int j = idx & 7;
    int lane = (idx >> 3) & 63;
    int ft = (idx >> 9) & 7;
    int kk = idx >> 12;
    int row = kk * 32 + (lane >> 4) * 8 + j;
    int col = ft * 16 + (lane & 15);
    const float* W = (m < 24) ? (w_rel + (size_t)m * 16384)
                              : (w_root + (size_t)(m - 24) * 16384);
    wb[i] = (unsigned short)f2bf(W[row * ND + col]);
}

__global__ __launch_bounds__(256) void k_count(const int* __restrict__ dst,
                                               const int* __restrict__ et,
                                               int* __restrict__ cnt) {
    int e = blockIdx.x * 256 + threadIdx.x;
    if (e >= NE) return;
    atomicAdd(&cnt[et[e] * NN + dst[e]], 1);
}

__global__ __launch_bounds__(256) void k_inv(const int* __restrict__ cnt,
                                             float* __restrict__ inv) {
    int i = blockIdx.x * 256 + threadIdx.x;
    if (i >= RN) return;
    int c = cnt[i];
    inv[i] = 1.0f / (float)(c > 1 ? c : 1);
}

__global__ __launch_bounds__(256) void k_scan1(const int* __restrict__ cnt,
                                               int* __restrict__ rowstart,
                                               int* __restrict__ bsum) {
    __shared__ int tmp[256];
    int t = threadIdx.x;
    int base = blockIdx.x * SCAN_BLK + t * 4;
    int v[4];
#pragma unroll
    for (int i = 0; i < 4; i++) v[i] = (base + i < RN) ? cnt[base + i] : 0;
    int local = v[0] + v[1] + v[2] + v[3];
    tmp[t] = local;
    __syncthreads();
    for (int off = 1; off < 256; off <<= 1) {
        int x = (t >= off) ? tmp[t - off] : 0;
        __syncthreads();
        tmp[t] += x;
        __syncthreads();
    }
    int run = tmp[t] - local;
    if (t == 255) bsum[blockIdx.x] = tmp[t];
#pragma unroll
    for (int i = 0; i < 4; i++) {
        if (base + i < RN) rowstart[base + i] = run;
        run += v[i];
    }
}

__global__ __launch_bounds__(256) void k_scan2(const int* __restrict__ bsum,
                                               int* __restrict__ boff) {
    __shared__ int tmp[256];
    int t = threadIdx.x;
    int v0 = (2 * t < NB) ? bsum[2 * t] : 0;
    int v1 = (2 * t + 1 < NB) ? bsum[2 * t + 1] : 0;
    int local = v0 + v1;
    tmp[t] = local;
    __syncthreads();
    for (int off = 1; off < 256; off <<= 1) {
        int x = (t >= off) ? tmp[t - off] : 0;
        __syncthreads();
        tmp[t] += x;
        __syncthreads();
    }
    int excl = tmp[t] - local;
    if (2 * t < NB) boff[2 * t] = excl;
    if (2 * t + 1 < NB) boff[2 * t + 1] = excl + v0;
}

__global__ __launch_bounds__(256) void k_scan3(int* __restrict__ rowstart,
                                               const int* __restrict__ boff) {
    int i = blockIdx.x * 256 + threadIdx.x;
    if (i < RN) rowstart[i] += boff[i >> 10];
    if (i == 0) rowstart[RN] = NE;
}

__global__ __launch_bounds__(256) void k_fill(const int* __restrict__ src,
                                              const int* __restrict__ dst,
                                              const int* __restrict__ et,
                                              const int* __restrict__ rowstart,
                                              int* __restrict__ cnt,
                                              int* __restrict__ adj) {
    int e = blockIdx.x * 256 + threadIdx.x;
    if (e >= NE) return;
    int seg = et[e] * NN + dst[e];
    int c = atomicSub(&cnt[seg], 1);
    adj[rowstart[seg] + c - 1] = src[e];
}

// Fused RGCN layer, MFMA edition. Block = 64 nodes. 4 waves, each owns a 16-row m-tile.
__global__ __launch_bounds__(256) void k_layer(const unsigned* __restrict__ h32,
                                               const int* __restrict__ adj,
                                               const int* __restrict__ rowstart,
                                               const float* __restrict__ inv,
                                               const unsigned short* __restrict__ wrel,
                                               const unsigned short* __restrict__ wroot,
                                               const float* __restrict__ bias,
                                               const float* __restrict__ gamma,
                                               const float* __restrict__ beta,
                                               float* __restrict__ out_f,
                                               unsigned* __restrict__ out_h,
                                               int add_res, int last) {
    __shared__ float SLF[64 * PADF];                 // 33792 B fp32 epilogue scratch
    unsigned short* SLB = (unsigned short*)SLF;      // aliased bf16 tile [64][PADB]
    unsigned* SLB32 = (unsigned*)SLF;

    int tid = threadIdx.x;
    int wave = tid >> 6, lane = tid & 63;
    int quad = lane >> 4, l15 = lane & 15;
    int n0 = blockIdx.x * 64;

    float4v acc[8];
#pragma unroll
    for (int i = 0; i < 8; i++) acc[i] = (float4v){0.f, 0.f, 0.f, 0.f};

    for (int r = 0; r < NR; r++) {
        // gather+mean into bf16 LDS tile (wave: 16 rows, lane: cols 2l,2l+1)
        for (int i = 0; i < 16; i++) {
            int row = wave * 16 + i;
            int g = n0 + row;
            float a0 = 0.f, a1 = 0.f;
            if (g < NN) {
                int seg = r * NN + g;
                int st = rowstart[seg], en = rowstart[seg + 1];
                float b0 = 0.f, b1 = 0.f, c0 = 0.f, c1 = 0.f, d0 = 0.f, d1 = 0.f;
                int p = st;
                for (; p + 3 < en; p += 4) {
                    int s0 = adj[p], s1 = adj[p + 1], s2 = adj[p + 2], s3 = adj[p + 3];
                    unsigned u0 = h32[s0 * 64 + lane];
                    unsigned u1 = h32[s1 * 64 + lane];
                    unsigned u2 = h32[s2 * 64 + lane];
                    unsigned u3 = h32[s3 * 64 + lane];
                    a0 += bflo(u0); a1 += bfhi(u0);
                    b0 += bflo(u1); b1 += bfhi(u1);
                    c0 += bflo(u2); c1 += bfhi(u2);
                    d0 += bflo(u3); d1 += bfhi(u3);
                }
                for (; p < en; p++) {
                    unsigned u = h32[adj[p] * 64 + lane];
                    a0 += bflo(u); a1 += bfhi(u);
                }
                float sc = inv[seg];
                a0 = (a0 + b0 + c0 + d0) * sc;
                a1 = (a1 + b1 + c1 + d1) * sc;
            }
            SLB32[row * (PADB / 2) + lane] = pack2(a0, a1);
        }
        __syncthreads();
        const unsigned short* WB = wrel + r * 16384;
#pragma unroll
        for (int kk = 0; kk < 4; kk++) {
            short8 af = *(const short8*)&SLB[(wave * 16 + l15) * PADB + kk * 32 + quad * 8];
#pragma unroll
            for (int ft = 0; ft < 8; ft++) {
                short8 bf = *(const short8*)&WB[((kk * 8 + ft) * 64 + lane) * 8];
                acc[ft] = __builtin_amdgcn_mfma_f32_16x16x32_bf16(af, bf, acc[ft], 0, 0, 0);
            }
        }
        __syncthreads();
    }

    // root transform: stage h tile (coalesced) then MFMA
#pragma unroll
    for (int i = 0; i < 16; i++) {
        int idx = tid + i * 256;                     // 4096 dwords
        int row = idx >> 6, dw = idx & 63;
        int g = n0 + row;
        SLB32[row * (PADB / 2) + dw] = (g < NN) ? h32[g * 64 + dw] : 0u;
    }
    __syncthreads();
#pragma unroll
    for (int kk = 0; kk < 4; kk++) {
        short8 af = *(const short8*)&SLB[(wave * 16 + l15) * PADB + kk * 32 + quad * 8];
#pragma unroll
        for (int ft = 0; ft < 8; ft++) {
            short8 bf = *(const short8*)&wroot[((kk * 8 + ft) * 64 + lane) * 8];
            acc[ft] = __builtin_amdgcn_mfma_f32_16x16x32_bf16(af, bf, acc[ft], 0, 0, 0);
        }
    }
    __syncthreads();

    // epilogue: acc (C layout: row=quad*4+reg, col=ft*16+l15) -> fp32 LDS
#pragma unroll
    for (int ft = 0; ft < 8; ft++)
#pragma unroll
        for (int rg = 0; rg < 4; rg++)
            SLF[(wave * 16 + quad * 4 + rg) * PADF + ft * 16 + l15] = acc[ft][rg];
    __syncthreads();

    float2 bia = *(const float2*)&bias[2 * lane];
    float2 gam = *(const float2*)&gamma[2 * lane];
    float2 bet = *(const float2*)&beta[2 * lane];

    for (int i = 0; i < 16; i++) {
        int row = wave * 16 + i;
        int g = n0 + row;
        if (g >= NN) continue;                       // wave-uniform
        float v0 = SLF[row * PADF + 2 * lane] + bia.x;
        float v1 = SLF[row * PADF + 2 * lane + 1] + bia.y;
        float s = v0 + v1;
#pragma unroll
        for (int off = 32; off > 0; off >>= 1) s += __shfl_xor(s, off, 64);
        float mu = s * (1.0f / ND);
        float e0 = v0 - mu, e1 = v1 - mu;
        float vs = e0 * e0 + e1 * e1;
#pragma unroll
        for (int off = 32; off > 0; off >>= 1) vs += __shfl_xor(vs, off, 64);
        float rr = rsqrtf(vs * (1.0f / ND) + LN_EPS);
        float o0 = fmaxf(e0 * rr * gam.x + bet.x, 0.0f);
        float o1 = fmaxf(e1 * rr * gam.y + bet.y, 0.0f);
        if (add_res) {
            unsigned u = h32[g * 64 + lane];
            o0 += bflo(u);
            o1 += bfhi(u);
        }
        if (last) {
            *(float2*)&out_f[(size_t)g * ND + 2 * lane] = make_float2(o0, o1);
        } else {
            out_h[g * 64 + lane] = pack2(o0, o1);
        }
    }
}

extern "C" void kernel_launch(void* const* d_in, const int* in_sizes, int n_in,
                              void* d_out, int out_size, void* d_ws, size_t ws_size,
                              hipStream_t stream) {
    const int*   x      = (const int*)d_in[0];
    const int*   ei     = (const int*)d_in[1];
    const int*   et     = (const int*)d_in[2];
    const float* emb    = (const float*)d_in[3];
    const float* w_rel  = (const float*)d_in[4];
    const float* w_root = (const float*)d_in[5];
    const float* bias   = (const float*)d_in[6];
    const float* gamma  = (const float*)d_in[7];
    const float* beta   = (const float*)d_in[8];
    float* out = (float*)d_out;

    char* ws = (char*)d_ws;
    unsigned* h_a      = (unsigned*)(ws);                    // 12.8 MB (bf16x2 packed)
    unsigned* h_b      = (unsigned*)(ws + 12800000);         // 12.8 MB
    int*      cnt      = (int*)     (ws + 25600000);         // 1.6 MB
    float*    inv      = (float*)   (ws + 27200000);         // 1.6 MB
    int*      rowstart = (int*)     (ws + 28800000);         // 1.6 MB + 4
    int*      bsum     = (int*)     (ws + 30400064);
    int*      boff     = (int*)     (ws + 30402048);
    int*      adj      = (int*)     (ws + 30404096);         // 6.4 MB
    unsigned short* wb = (unsigned short*)(ws + 36804096);   // 884736 B

    const int* src = ei;
    const int* dst = ei + NE;

    hipMemsetAsync(cnt, 0, RN * sizeof(int), stream);
    k_gather<<<(NN * 64 + 255) / 256, 256, 0, stream>>>(x, emb, h_a);
    k_wprep<<<(27 * 16384 + 255) / 256, 256, 0, stream>>>(w_rel, w_root, wb);
    k_count<<<(NE + 255) / 256, 256, 0, stream>>>(dst, et, cnt);
    k_inv<<<(RN + 255) / 256, 256, 0, stream>>>(cnt, inv);
    k_scan1<<<NB, 256, 0, stream>>>(cnt, rowstart, bsum);
    k_scan2<<<1, 256, 0, stream>>>(bsum, boff);
    k_scan3<<<(RN + 255) / 256, 256, 0, stream>>>(rowstart, boff);
    k_fill<<<(NE + 255) / 256, 256, 0, stream>>>(src, dst, et, rowstart, cnt, adj);

    unsigned* h_cur = h_a;
    unsigned* h_nxt = h_b;
    for (int l = 0; l < NL; l++) {
        k_layer<<<(NN + 63) / 64, 256, 0, stream>>>(
            h_cur, adj, rowstart, inv,
            wb + (size_t)l * 8 * 16384, wb + (size_t)(24 + l) * 16384,
            bias + l * ND, gamma + l * ND, beta + l * ND,
            out, h_nxt, l > 0, l == NL - 1);
        unsigned* t = h_cur; h_cur = h_nxt; h_nxt = t;
    }
}

// Round 5
// 836.827 us; speedup vs baseline: 5.1320x; 1.4100x over previous
//
#include <hip/hip_runtime.h>

#define NN 50000
#define NE 1600000
#define NR 8
#define ND 128
#define NL 3
#define RN (NR * NN)
#define SCAN_BLK 1024
#define NB ((RN + SCAN_BLK - 1) / SCAN_BLK)  // 391
#define LN_EPS 1e-5f
#define PADB 136   // bf16 elems per LDS tile row (row stride 272 B)
#define PADF 132   // f32 elems per epilogue scratch row

typedef __attribute__((ext_vector_type(8))) short short8;
typedef __attribute__((ext_vector_type(4))) float float4v;

__device__ __forceinline__ float bflo(unsigned u) { return __uint_as_float(u << 16); }
__device__ __forceinline__ float bfhi(unsigned u) { return __uint_as_float(u & 0xFFFF0000u); }
__device__ __forceinline__ unsigned f2bf(float f) {
    unsigned u = __float_as_uint(f);
    return (u + 0x7FFFu + ((u >> 16) & 1u)) >> 16;   // RNE
}
__device__ __forceinline__ unsigned pack2(float lo, float hi) {
    return f2bf(lo) | (f2bf(hi) << 16);
}

// h(bf16x2 packed) = emb[x]
__global__ __launch_bounds__(256) void k_gather(const int* __restrict__ x,
                                                const float* __restrict__ emb,
                                                unsigned* __restrict__ h) {
    int i = blockIdx.x * 256 + threadIdx.x;       // over NN*64 dwords
    if (i >= NN * 64) return;
    int n = i >> 6, dw = i & 63;
    float2 v = *(const float2*)&emb[(size_t)x[n] * ND + 2 * dw];
    h[i] = pack2(v.x, v.y);
}

// weights -> bf16 B-fragment layout: wb[m][((kk*8+ft)*64+lane)*8+j] = W_m[kk*32+(lane>>4)*8+j][ft*16+(lane&15)]
__global__ __launch_bounds__(256) void k_wprep(const float* __restrict__ w_rel,
                                               const float* __restrict__ w_root,
                                               unsigned short* __restrict__ wb) {
    int i = blockIdx.x * 256 + threadIdx.x;
    if (i >= 27 * 16384) return;
    int m = i >> 14;
    int idx = i & 16383;
    int j = idx & 7;
    int lane = (idx >> 3) & 63;
    int ft = (idx >> 9) & 7;
    int kk = idx >> 12;
    int row = kk * 32 + (lane >> 4) * 8 + j;
    int col = ft * 16 + (lane & 15);
    const float* W = (m < 24) ? (w_rel + (size_t)m * 16384)
                              : (w_root + (size_t)(m - 24) * 16384);
    wb[i] = (unsigned short)f2bf(W[row * ND + col]);
}

__global__ __launch_bounds__(256) void k_count(const int* __restrict__ dst,
                                               const int* __restrict__ et,
                                               int* __restrict__ cnt) {
    int e = blockIdx.x * 256 + threadIdx.x;
    if (e >= NE) return;
    atomicAdd(&cnt[et[e] * NN + dst[e]], 1);
}

__global__ __launch_bounds__(256) void k_inv(const int* __restrict__ cnt,
                                             float* __restrict__ inv) {
    int i = blockIdx.x * 256 + threadIdx.x;
    if (i >= RN) return;
    int c = cnt[i];
    inv[i] = 1.0f / (float)(c > 1 ? c : 1);
}

__global__ __launch_bounds__(256) void k_scan1(const int* __restrict__ cnt,
                                               int* __restrict__ rowstart,
                                               int* __restrict__ bsum) {
    __shared__ int tmp[256];
    int t = threadIdx.x;
    int base = blockIdx.x * SCAN_BLK + t * 4;
    int v[4];
#pragma unroll
    for (int i = 0; i < 4; i++) v[i] = (base + i < RN) ? cnt[base + i] : 0;
    int local = v[0] + v[1] + v[2] + v[3];
    tmp[t] = local;
    __syncthreads();
    for (int off = 1; off < 256; off <<= 1) {
        int x = (t >= off) ? tmp[t - off] : 0;
        __syncthreads();
        tmp[t] += x;
        __syncthreads();
    }
    int run = tmp[t] - local;
    if (t == 255) bsum[blockIdx.x] = tmp[t];
#pragma unroll
    for (int i = 0; i < 4; i++) {
        if (base + i < RN) rowstart[base + i] = run;
        run += v[i];
    }
}

__global__ __launch_bounds__(256) void k_scan2(const int* __restrict__ bsum,
                                               int* __restrict__ boff) {
    __shared__ int tmp[256];
    int t = threadIdx.x;
    int v0 = (2 * t < NB) ? bsum[2 * t] : 0;
    int v1 = (2 * t + 1 < NB) ? bsum[2 * t + 1] : 0;
    int local = v0 + v1;
    tmp[t] = local;
    __syncthreads();
    for (int off = 1; off < 256; off <<= 1) {
        int x = (t >= off) ? tmp[t - off] : 0;
        __syncthreads();
        tmp[t] += x;
        __syncthreads();
    }
    int excl = tmp[t] - local;
    if (2 * t < NB) boff[2 * t] = excl;
    if (2 * t + 1 < NB) boff[2 * t + 1] = excl + v0;
}

__global__ __launch_bounds__(256) void k_scan3(int* __restrict__ rowstart,
                                               const int* __restrict__ boff) {
    int i = blockIdx.x * 256 + threadIdx.x;
    if (i < RN) rowstart[i] += boff[i >> 10];
    if (i == 0) rowstart[RN] = NE;
}

__global__ __launch_bounds__(256) void k_fill(const int* __restrict__ src,
                                              const int* __restrict__ dst,
                                              const int* __restrict__ et,
                                              const int* __restrict__ rowstart,
                                              int* __restrict__ cnt,
                                              int* __restrict__ adj) {
    int e = blockIdx.x * 256 + threadIdx.x;
    if (e >= NE) return;
    int seg = et[e] * NN + dst[e];
    int c = atomicSub(&cnt[seg], 1);
    adj[rowstart[seg] + c - 1] = src[e];
}

// Fused RGCN layer, MFMA edition. Block = 64 nodes, 4 waves, wave owns 16-row m-tile.
// Gather: 16-lane quad groups, one row per quad (4 concurrent CSR chains/wave), dwordx4 loads.
__global__ __launch_bounds__(256) void k_layer(const unsigned* __restrict__ h32,
                                               const int* __restrict__ adj,
                                               const int* __restrict__ rowstart,
                                               const float* __restrict__ inv,
                                               const unsigned short* __restrict__ wrel,
                                               const unsigned short* __restrict__ wroot,
                                               const float* __restrict__ bias,
                                               const float* __restrict__ gamma,
                                               const float* __restrict__ beta,
                                               float* __restrict__ out_f,
                                               unsigned* __restrict__ out_h,
                                               int add_res, int last) {
    __shared__ float SLF[64 * PADF];                 // 33792 B fp32 epilogue scratch
    unsigned short* SLB = (unsigned short*)SLF;      // aliased bf16 tile [64][PADB]
    unsigned* SLB32 = (unsigned*)SLF;

    int tid = threadIdx.x;
    int wave = tid >> 6, lane = tid & 63;
    int quad = lane >> 4, l15 = lane & 15;
    int n0 = blockIdx.x * 64;

    float4v acc[8];
#pragma unroll
    for (int i = 0; i < 8; i++) acc[i] = (float4v){0.f, 0.f, 0.f, 0.f};

    for (int r = 0; r < NR; r++) {
        // gather+mean: 4 batches of 4 concurrent rows per wave; quad owns a row,
        // lane l15 covers dwords [l15*4, l15*4+4) of the 64-dword feature row.
        for (int b = 0; b < 4; b++) {
            int row = wave * 16 + b * 4 + quad;
            int g = n0 + row;
            float a0 = 0.f, a1 = 0.f, a2 = 0.f, a3 = 0.f,
                  a4 = 0.f, a5 = 0.f, a6 = 0.f, a7 = 0.f;
            if (g < NN) {
                int seg = r * NN + g;
                int st = rowstart[seg], en = rowstart[seg + 1];
                st = st < 0 ? 0 : st;
                en = en > NE ? NE : en;
                float c0 = 0.f, c1 = 0.f, c2 = 0.f, c3 = 0.f,
                      c4 = 0.f, c5 = 0.f, c6 = 0.f, c7 = 0.f;
                int p = st;
                for (; p + 1 < en; p += 2) {
                    unsigned s0 = (unsigned)adj[p], s1 = (unsigned)adj[p + 1];
                    s0 = s0 < NN ? s0 : NN - 1;
                    s1 = s1 < NN ? s1 : NN - 1;
                    uint4 u0 = *(const uint4*)&h32[(size_t)s0 * 64 + l15 * 4];
                    uint4 u1 = *(const uint4*)&h32[(size_t)s1 * 64 + l15 * 4];
                    a0 += bflo(u0.x); a1 += bfhi(u0.x);
                    a2 += bflo(u0.y); a3 += bfhi(u0.y);
                    a4 += bflo(u0.z); a5 += bfhi(u0.z);
                    a6 += bflo(u0.w); a7 += bfhi(u0.w);
                    c0 += bflo(u1.x); c1 += bfhi(u1.x);
                    c2 += bflo(u1.y); c3 += bfhi(u1.y);
                    c4 += bflo(u1.z); c5 += bfhi(u1.z);
                    c6 += bflo(u1.w); c7 += bfhi(u1.w);
                }
                if (p < en) {
                    unsigned s0 = (unsigned)adj[p];
                    s0 = s0 < NN ? s0 : NN - 1;
                    uint4 u0 = *(const uint4*)&h32[(size_t)s0 * 64 + l15 * 4];
                    a0 += bflo(u0.x); a1 += bfhi(u0.x);
                    a2 += bflo(u0.y); a3 += bfhi(u0.y);
                    a4 += bflo(u0.z); a5 += bfhi(u0.z);
                    a6 += bflo(u0.w); a7 += bfhi(u0.w);
                }
                float sc = inv[seg];
                a0 = (a0 + c0) * sc; a1 = (a1 + c1) * sc;
                a2 = (a2 + c2) * sc; a3 = (a3 + c3) * sc;
                a4 = (a4 + c4) * sc; a5 = (a5 + c5) * sc;
                a6 = (a6 + c6) * sc; a7 = (a7 + c7) * sc;
            }
            uint4 w;
            w.x = pack2(a0, a1); w.y = pack2(a2, a3);
            w.z = pack2(a4, a5); w.w = pack2(a6, a7);
            *(uint4*)&SLB32[row * (PADB / 2) + l15 * 4] = w;
        }
        __syncthreads();
        const unsigned short* WB = wrel + r * 16384;
#pragma unroll
        for (int kk = 0; kk < 4; kk++) {
            short8 af = *(const short8*)&SLB[(wave * 16 + l15) * PADB + kk * 32 + quad * 8];
#pragma unroll
            for (int ft = 0; ft < 8; ft++) {
                short8 bf = *(const short8*)&WB[((kk * 8 + ft) * 64 + lane) * 8];
                acc[ft] = __builtin_amdgcn_mfma_f32_16x16x32_bf16(af, bf, acc[ft], 0, 0, 0);
            }
        }
        __syncthreads();
    }

    // root transform: stage h tile (coalesced) then MFMA
#pragma unroll
    for (int i = 0; i < 16; i++) {
        int idx = tid + i * 256;                     // 4096 dwords
        int row = idx >> 6, dw = idx & 63;
        int g = n0 + row;
        SLB32[row * (PADB / 2) + dw] = (g < NN) ? h32[(size_t)g * 64 + dw] : 0u;
    }
    __syncthreads();
#pragma unroll
    for (int kk = 0; kk < 4; kk++) {
        short8 af = *(const short8*)&SLB[(wave * 16 + l15) * PADB + kk * 32 + quad * 8];
#pragma unroll
        for (int ft = 0; ft < 8; ft++) {
            short8 bf = *(const short8*)&wroot[((kk * 8 + ft) * 64 + lane) * 8];
            acc[ft] = __builtin_amdgcn_mfma_f32_16x16x32_bf16(af, bf, acc[ft], 0, 0, 0);
        }
    }
    __syncthreads();

    // epilogue: acc (C layout: row=quad*4+reg, col=ft*16+l15) -> fp32 LDS
#pragma unroll
    for (int ft = 0; ft < 8; ft++)
#pragma unroll
        for (int rg = 0; rg < 4; rg++)
            SLF[(wave * 16 + quad * 4 + rg) * PADF + ft * 16 + l15] = acc[ft][rg];
    __syncthreads();

    float2 bia = *(const float2*)&bias[2 * lane];
    float2 gam = *(const float2*)&gamma[2 * lane];
    float2 bet = *(const float2*)&beta[2 * lane];

    for (int i = 0; i < 16; i++) {
        int row = wave * 16 + i;
        int g = n0 + row;
        if (g >= NN) continue;                       // wave-uniform
        float v0 = SLF[row * PADF + 2 * lane] + bia.x;
        float v1 = SLF[row * PADF + 2 * lane + 1] + bia.y;
        float s = v0 + v1;
#pragma unroll
        for (int off = 32; off > 0; off >>= 1) s += __shfl_xor(s, off, 64);
        float mu = s * (1.0f / ND);
        float e0 = v0 - mu, e1 = v1 - mu;
        float vs = e0 * e0 + e1 * e1;
#pragma unroll
        for (int off = 32; off > 0; off >>= 1) vs += __shfl_xor(vs, off, 64);
        float rr = rsqrtf(vs * (1.0f / ND) + LN_EPS);
        float o0 = fmaxf(e0 * rr * gam.x + bet.x, 0.0f);
        float o1 = fmaxf(e1 * rr * gam.y + bet.y, 0.0f);
        if (add_res) {
            unsigned u = h32[(size_t)g * 64 + lane];
            o0 += bflo(u);
            o1 += bfhi(u);
        }
        if (last) {
            *(float2*)&out_f[(size_t)g * ND + 2 * lane] = make_float2(o0, o1);
        } else {
            out_h[(size_t)g * 64 + lane] = pack2(o0, o1);
        }
    }
}

extern "C" void kernel_launch(void* const* d_in, const int* in_sizes, int n_in,
                              void* d_out, int out_size, void* d_ws, size_t ws_size,
                              hipStream_t stream) {
    const int*   x      = (const int*)d_in[0];
    const int*   ei     = (const int*)d_in[1];
    const int*   et     = (const int*)d_in[2];
    const float* emb    = (const float*)d_in[3];
    const float* w_rel  = (const float*)d_in[4];
    const float* w_root = (const float*)d_in[5];
    const float* bias   = (const float*)d_in[6];
    const float* gamma  = (const float*)d_in[7];
    const float* beta   = (const float*)d_in[8];
    float* out = (float*)d_out;

    char* ws = (char*)d_ws;
    unsigned* h_a      = (unsigned*)(ws);                    // 12.8 MB (bf16x2 packed)
    unsigned* h_b      = (unsigned*)(ws + 12800000);         // 12.8 MB
    int*      cnt      = (int*)     (ws + 25600000);         // 1.6 MB
    float*    inv      = (float*)   (ws + 27200000);         // 1.6 MB
    int*      rowstart = (int*)     (ws + 28800000);         // 1.6 MB + 4
    int*      bsum     = (int*)     (ws + 30400064);
    int*      boff     = (int*)     (ws + 30402048);
    int*      adj      = (int*)     (ws + 30404096);         // 6.4 MB
    unsigned short* wb = (unsigned short*)(ws + 36804096);   // 884736 B

    const int* src = ei;
    const int* dst = ei + NE;

    hipMemsetAsync(cnt, 0, RN * sizeof(int), stream);
    k_gather<<<(NN * 64 + 255) / 256, 256, 0, stream>>>(x, emb, h_a);
    k_wprep<<<(27 * 16384 + 255) / 256, 256, 0, stream>>>(w_rel, w_root, wb);
    k_count<<<(NE + 255) / 256, 256, 0, stream>>>(dst, et, cnt);
    k_inv<<<(RN + 255) / 256, 256, 0, stream>>>(cnt, inv);
    k_scan1<<<NB, 256, 0, stream>>>(cnt, rowstart, bsum);
    k_scan2<<<1, 256, 0, stream>>>(bsum, boff);
    k_scan3<<<(RN + 255) / 256, 256, 0, stream>>>(rowstart, boff);
    k_fill<<<(NE + 255) / 256, 256, 0, stream>>>(src, dst, et, rowstart, cnt, adj);

    unsigned* h_cur = h_a;
    unsigned* h_nxt = h_b;
    for (int l = 0; l < NL; l++) {
        k_layer<<<(NN + 63) / 64, 256, 0, stream>>>(
            h_cur, adj, rowstart, inv,
            wb + (size_t)l * 8 * 16384, wb + (size_t)(24 + l) * 16384,
            bias + l * ND, gamma + l * ND, beta + l * ND,
            out, h_nxt, l > 0, l == NL - 1);
        unsigned* t = h_cur; h_cur = h_nxt; h_nxt = t;
    }
}

// Round 6
// 817.185 us; speedup vs baseline: 5.2553x; 1.0240x over previous
//
#include <hip/hip_runtime.h>

#define NN 50000
#define NE 1600000
#define NR 8
#define ND 128
#define NL 3
#define RN (NR * NN)
#define SCAN_BLK 1024
#define NB ((RN + SCAN_BLK - 1) / SCAN_BLK)  // 391
#define LN_EPS 1e-5f
#define PADB 136   // bf16 elems per LDS tile row (row stride 272 B)
#define PADF 132   // f32 elems per epilogue scratch row

typedef __attribute__((ext_vector_type(8))) short short8;
typedef __attribute__((ext_vector_type(4))) float float4v;

__device__ __forceinline__ float bflo(unsigned u) { return __uint_as_float(u << 16); }
__device__ __forceinline__ float bfhi(unsigned u) { return __uint_as_float(u & 0xFFFF0000u); }
__device__ __forceinline__ unsigned f2bf(float f) {
    unsigned u = __float_as_uint(f);
    return (u + 0x7FFFu + ((u >> 16) & 1u)) >> 16;   // RNE
}
__device__ __forceinline__ unsigned pack2(float lo, float hi) {
    return f2bf(lo) | (f2bf(hi) << 16);
}

// h(bf16x2 packed) = emb[x]
__global__ __launch_bounds__(256) void k_gather(const int* __restrict__ x,
                                                const float* __restrict__ emb,
                                                unsigned* __restrict__ h) {
    int i = blockIdx.x * 256 + threadIdx.x;       // over NN*64 dwords
    if (i >= NN * 64) return;
    int n = i >> 6, dw = i & 63;
    float2 v = *(const float2*)&emb[(size_t)x[n] * ND + 2 * dw];
    h[i] = pack2(v.x, v.y);
}

// weights -> bf16 B-fragment layout: wb[m][((kk*8+ft)*64+lane)*8+j] = W_m[kk*32+(lane>>4)*8+j][ft*16+(lane&15)]
__global__ __launch_bounds__(256) void k_wprep(const float* __restrict__ w_rel,
                                               const float* __restrict__ w_root,
                                               unsigned short* __restrict__ wb) {
    int i = blockIdx.x * 256 + threadIdx.x;
    if (i >= 27 * 16384) return;
    int m = i >> 14;
    int idx = i & 16383;
    int j = idx & 7;
    int lane = (idx >> 3) & 63;
    int ft = (idx >> 9) & 7;
    int kk = idx >> 12;
    int row = kk * 32 + (lane >> 4) * 8 + j;
    int col = ft * 16 + (lane & 15);
    const float* W = (m < 24) ? (w_rel + (size_t)m * 16384)
                              : (w_root + (size_t)(m - 24) * 16384);
    wb[i] = (unsigned short)f2bf(W[row * ND + col]);
}

__global__ __launch_bounds__(256) void k_count(const int* __restrict__ dst,
                                               const int* __restrict__ et,
                                               int* __restrict__ cnt) {
    int e = blockIdx.x * 256 + threadIdx.x;
    if (e >= NE) return;
    atomicAdd(&cnt[et[e] * NN + dst[e]], 1);
}

__global__ __launch_bounds__(256) void k_inv(const int* __restrict__ cnt,
                                             float* __restrict__ inv) {
    int i = blockIdx.x * 256 + threadIdx.x;
    if (i >= RN) return;
    int c = cnt[i];
    inv[i] = 1.0f / (float)(c > 1 ? c : 1);
}

__global__ __launch_bounds__(256) void k_scan1(const int* __restrict__ cnt,
                                               int* __restrict__ rowstart,
                                               int* __restrict__ bsum) {
    __shared__ int tmp[256];
    int t = threadIdx.x;
    int base = blockIdx.x * SCAN_BLK + t * 4;
    int v[4];
#pragma unroll
    for (int i = 0; i < 4; i++) v[i] = (base + i < RN) ? cnt[base + i] : 0;
    int local = v[0] + v[1] + v[2] + v[3];
    tmp[t] = local;
    __syncthreads();
    for (int off = 1; off < 256; off <<= 1) {
        int x = (t >= off) ? tmp[t - off] : 0;
        __syncthreads();
        tmp[t] += x;
        __syncthreads();
    }
    int run = tmp[t] - local;
    if (t == 255) bsum[blockIdx.x] = tmp[t];
#pragma unroll
    for (int i = 0; i < 4; i++) {
        if (base + i < RN) rowstart[base + i] = run;
        run += v[i];
    }
}

__global__ __launch_bounds__(256) void k_scan2(const int* __restrict__ bsum,
                                               int* __restrict__ boff) {
    __shared__ int tmp[256];
    int t = threadIdx.x;
    int v0 = (2 * t < NB) ? bsum[2 * t] : 0;
    int v1 = (2 * t + 1 < NB) ? bsum[2 * t + 1] : 0;
    int local = v0 + v1;
    tmp[t] = local;
    __syncthreads();
    for (int off = 1; off < 256; off <<= 1) {
        int x = (t >= off) ? tmp[t - off] : 0;
        __syncthreads();
        tmp[t] += x;
        __syncthreads();
    }
    int excl = tmp[t] - local;
    if (2 * t < NB) boff[2 * t] = excl;
    if (2 * t + 1 < NB) boff[2 * t + 1] = excl + v0;
}

__global__ __launch_bounds__(256) void k_scan3(int* __restrict__ rowstart,
                                               const int* __restrict__ boff) {
    int i = blockIdx.x * 256 + threadIdx.x;
    if (i < RN) rowstart[i] += boff[i >> 10];
    if (i == 0) rowstart[RN] = NE;
}

__global__ __launch_bounds__(256) void k_fill(const int* __restrict__ src,
                                              const int* __restrict__ dst,
                                              const int* __restrict__ et,
                                              const int* __restrict__ rowstart,
                                              int* __restrict__ cnt,
                                              int* __restrict__ adj) {
    int e = blockIdx.x * 256 + threadIdx.x;
    if (e >= NE) return;
    int seg = et[e] * NN + dst[e];
    int c = atomicSub(&cnt[seg], 1);
    adj[rowstart[seg] + c - 1] = src[e];
}

// Fused RGCN layer. Block = 64 nodes, 8 waves (512 threads).
// Gather/epilogue use all 8 waves (2 serialized batches of 4 quad-chains each);
// MFMA runs on waves 0-3 (each owns a 16-row m-tile).
__global__ __launch_bounds__(512) void k_layer(const unsigned* __restrict__ h32,
                                               const int* __restrict__ adj,
                                               const int* __restrict__ rowstart,
                                               const float* __restrict__ inv,
                                               const unsigned short* __restrict__ wrel,
                                               const unsigned short* __restrict__ wroot,
                                               const float* __restrict__ bias,
                                               const float* __restrict__ gamma,
                                               const float* __restrict__ beta,
                                               float* __restrict__ out_f,
                                               unsigned* __restrict__ out_h,
                                               int add_res, int last) {
    __shared__ float SLF[64 * PADF];                 // 33792 B fp32 epilogue scratch
    unsigned short* SLB = (unsigned short*)SLF;      // aliased bf16 tile [64][PADB]
    unsigned* SLB32 = (unsigned*)SLF;

    int tid = threadIdx.x;
    int wave = tid >> 6, lane = tid & 63;
    int quad = lane >> 4, l15 = lane & 15;
    int n0 = blockIdx.x * 64;

    float4v acc[8];
#pragma unroll
    for (int i = 0; i < 8; i++) acc[i] = (float4v){0.f, 0.f, 0.f, 0.f};

    for (int r = 0; r < NR; r++) {
        // gather+mean: 2 batches of 4 concurrent rows per wave (8 waves cover 64 rows)
        for (int b = 0; b < 2; b++) {
            int row = wave * 8 + b * 4 + quad;
            int g = n0 + row;
            float a0 = 0.f, a1 = 0.f, a2 = 0.f, a3 = 0.f,
                  a4 = 0.f, a5 = 0.f, a6 = 0.f, a7 = 0.f;
            if (g < NN) {
                int seg = r * NN + g;
                int st = rowstart[seg], en = rowstart[seg + 1];
                st = st < 0 ? 0 : st;
                en = en > NE ? NE : en;
                float c0 = 0.f, c1 = 0.f, c2 = 0.f, c3 = 0.f,
                      c4 = 0.f, c5 = 0.f, c6 = 0.f, c7 = 0.f;
                int p = st;
                for (; p + 1 < en; p += 2) {
                    unsigned s0 = (unsigned)adj[p], s1 = (unsigned)adj[p + 1];
                    s0 = s0 < NN ? s0 : NN - 1;
                    s1 = s1 < NN ? s1 : NN - 1;
                    uint4 u0 = *(const uint4*)&h32[(size_t)s0 * 64 + l15 * 4];
                    uint4 u1 = *(const uint4*)&h32[(size_t)s1 * 64 + l15 * 4];
                    a0 += bflo(u0.x); a1 += bfhi(u0.x);
                    a2 += bflo(u0.y); a3 += bfhi(u0.y);
                    a4 += bflo(u0.z); a5 += bfhi(u0.z);
                    a6 += bflo(u0.w); a7 += bfhi(u0.w);
                    c0 += bflo(u1.x); c1 += bfhi(u1.x);
                    c2 += bflo(u1.y); c3 += bfhi(u1.y);
                    c4 += bflo(u1.z); c5 += bfhi(u1.z);
                    c6 += bflo(u1.w); c7 += bfhi(u1.w);
                }
                if (p < en) {
                    unsigned s0 = (unsigned)adj[p];
                    s0 = s0 < NN ? s0 : NN - 1;
                    uint4 u0 = *(const uint4*)&h32[(size_t)s0 * 64 + l15 * 4];
                    a0 += bflo(u0.x); a1 += bfhi(u0.x);
                    a2 += bflo(u0.y); a3 += bfhi(u0.y);
                    a4 += bflo(u0.z); a5 += bfhi(u0.z);
                    a6 += bflo(u0.w); a7 += bfhi(u0.w);
                }
                float sc = inv[seg];
                a0 = (a0 + c0) * sc; a1 = (a1 + c1) * sc;
                a2 = (a2 + c2) * sc; a3 = (a3 + c3) * sc;
                a4 = (a4 + c4) * sc; a5 = (a5 + c5) * sc;
                a6 = (a6 + c6) * sc; a7 = (a7 + c7) * sc;
            }
            uint4 w;
            w.x = pack2(a0, a1); w.y = pack2(a2, a3);
            w.z = pack2(a4, a5); w.w = pack2(a6, a7);
            *(uint4*)&SLB32[row * (PADB / 2) + l15 * 4] = w;
        }
        __syncthreads();
        if (wave < 4) {
            const unsigned short* WB = wrel + r * 16384;
#pragma unroll
            for (int kk = 0; kk < 4; kk++) {
                short8 af = *(const short8*)&SLB[(wave * 16 + l15) * PADB + kk * 32 + quad * 8];
#pragma unroll
                for (int ft = 0; ft < 8; ft++) {
                    short8 bf = *(const short8*)&WB[((kk * 8 + ft) * 64 + lane) * 8];
                    acc[ft] = __builtin_amdgcn_mfma_f32_16x16x32_bf16(af, bf, acc[ft], 0, 0, 0);
                }
            }
        }
        __syncthreads();
    }

    // root transform: stage h tile (coalesced) then MFMA
#pragma unroll
    for (int i = 0; i < 8; i++) {
        int idx = tid + i * 512;                     // 4096 dwords
        int row = idx >> 6, dw = idx & 63;
        int g = n0 + row;
        SLB32[row * (PADB / 2) + dw] = (g < NN) ? h32[(size_t)g * 64 + dw] : 0u;
    }
    __syncthreads();
    if (wave < 4) {
#pragma unroll
        for (int kk = 0; kk < 4; kk++) {
            short8 af = *(const short8*)&SLB[(wave * 16 + l15) * PADB + kk * 32 + quad * 8];
#pragma unroll
            for (int ft = 0; ft < 8; ft++) {
                short8 bf = *(const short8*)&wroot[((kk * 8 + ft) * 64 + lane) * 8];
                acc[ft] = __builtin_amdgcn_mfma_f32_16x16x32_bf16(af, bf, acc[ft], 0, 0, 0);
            }
        }
    }
    __syncthreads();

    // epilogue: acc (C layout: row=quad*4+reg, col=ft*16+l15) -> fp32 LDS (waves 0-3)
    if (wave < 4) {
#pragma unroll
        for (int ft = 0; ft < 8; ft++)
#pragma unroll
            for (int rg = 0; rg < 4; rg++)
                SLF[(wave * 16 + quad * 4 + rg) * PADF + ft * 16 + l15] = acc[ft][rg];
    }
    __syncthreads();

    float2 bia = *(const float2*)&bias[2 * lane];
    float2 gam = *(const float2*)&gamma[2 * lane];
    float2 bet = *(const float2*)&beta[2 * lane];

    for (int i = 0; i < 8; i++) {
        int row = wave * 8 + i;
        int g = n0 + row;
        if (g >= NN) continue;                       // wave-uniform
        float v0 = SLF[row * PADF + 2 * lane] + bia.x;
        float v1 = SLF[row * PADF + 2 * lane + 1] + bia.y;
        float s = v0 + v1;
#pragma unroll
        for (int off = 32; off > 0; off >>= 1) s += __shfl_xor(s, off, 64);
        float mu = s * (1.0f / ND);
        float e0 = v0 - mu, e1 = v1 - mu;
        float vs = e0 * e0 + e1 * e1;
#pragma unroll
        for (int off = 32; off > 0; off >>= 1) vs += __shfl_xor(vs, off, 64);
        float rr = rsqrtf(vs * (1.0f / ND) + LN_EPS);
        float o0 = fmaxf(e0 * rr * gam.x + bet.x, 0.0f);
        float o1 = fmaxf(e1 * rr * gam.y + bet.y, 0.0f);
        if (add_res) {
            unsigned u = h32[(size_t)g * 64 + lane];
            o0 += bflo(u);
            o1 += bfhi(u);
        }
        if (last) {
            *(float2*)&out_f[(size_t)g * ND + 2 * lane] = make_float2(o0, o1);
        } else {
            out_h[(size_t)g * 64 + lane] = pack2(o0, o1);
        }
    }
}

extern "C" void kernel_launch(void* const* d_in, const int* in_sizes, int n_in,
                              void* d_out, int out_size, void* d_ws, size_t ws_size,
                              hipStream_t stream) {
    const int*   x      = (const int*)d_in[0];
    const int*   ei     = (const int*)d_in[1];
    const int*   et     = (const int*)d_in[2];
    const float* emb    = (const float*)d_in[3];
    const float* w_rel  = (const float*)d_in[4];
    const float* w_root = (const float*)d_in[5];
    const float* bias   = (const float*)d_in[6];
    const float* gamma  = (const float*)d_in[7];
    const float* beta   = (const float*)d_in[8];
    float* out = (float*)d_out;

    char* ws = (char*)d_ws;
    unsigned* h_a      = (unsigned*)(ws);                    // 12.8 MB (bf16x2 packed)
    unsigned* h_b      = (unsigned*)(ws + 12800000);         // 12.8 MB
    int*      cnt      = (int*)     (ws + 25600000);         // 1.6 MB
    float*    inv      = (float*)   (ws + 27200000);         // 1.6 MB
    int*      rowstart = (int*)     (ws + 28800000);         // 1.6 MB + 4
    int*      bsum     = (int*)     (ws + 30400064);
    int*      boff     = (int*)     (ws + 30402048);
    int*      adj      = (int*)     (ws + 30404096);         // 6.4 MB
    unsigned short* wb = (unsigned short*)(ws + 36804096);   // 884736 B

    const int* src = ei;
    const int* dst = ei + NE;

    hipMemsetAsync(cnt, 0, RN * sizeof(int), stream);
    k_gather<<<(NN * 64 + 255) / 256, 256, 0, stream>>>(x, emb, h_a);
    k_wprep<<<(27 * 16384 + 255) / 256, 256, 0, stream>>>(w_rel, w_root, wb);
    k_count<<<(NE + 255) / 256, 256, 0, stream>>>(dst, et, cnt);
    k_inv<<<(RN + 255) / 256, 256, 0, stream>>>(cnt, inv);
    k_scan1<<<NB, 256, 0, stream>>>(cnt, rowstart, bsum);
    k_scan2<<<1, 256, 0, stream>>>(bsum, boff);
    k_scan3<<<(RN + 255) / 256, 256, 0, stream>>>(rowstart, boff);
    k_fill<<<(NE + 255) / 256, 256, 0, stream>>>(src, dst, et, rowstart, cnt, adj);

    unsigned* h_cur = h_a;
    unsigned* h_nxt = h_b;
    for (int l = 0; l < NL; l++) {
        k_layer<<<(NN + 63) / 64, 512, 0, stream>>>(
            h_cur, adj, rowstart, inv,
            wb + (size_t)l * 8 * 16384, wb + (size_t)(24 + l) * 16384,
            bias + l * ND, gamma + l * ND, beta + l * ND,
            out, h_nxt, l > 0, l == NL - 1);
        unsigned* t = h_cur; h_cur = h_nxt; h_nxt = t;
    }
}